// Round 10
// baseline (335.341 us; speedup 1.0000x reference)
//
#include <hip/hip_runtime.h>
#include <hip/hip_bf16.h>

#define NN 50000
#define NE 1600000
#define FF 128
#define CC 16
#define NB ((NN + 63) / 64)       // 782 dst-buckets of 64 nodes
#define NBLK 1024                 // partition blocks for the sort (4x parallelism; blocks >=1000 idle)
#define CH 1600                   // edges per partition block (16B-aligned; 1000*1600 == NE exactly)
#define EBUF 4096                 // bsort LDS edge cache (16KB; bucket avg 2048, max ~2400)

using bf16 = __hip_bfloat16;
using bf16x8 = __attribute__((ext_vector_type(8))) short;   // 8 bf16 = 4 VGPRs
using f32x4  = __attribute__((ext_vector_type(4))) float;

// Runtime-dtype load: isbf selects bf16 vs f32 interpretation of p.
static __device__ __forceinline__ float ldf(const void* p, int i, int isbf){
    return isbf ? __bfloat162float(((const bf16*)p)[i]) : ((const float*)p)[i];
}
static __device__ __forceinline__ float bflo(unsigned u){
    union{unsigned x; float f;} c; c.x = u << 16; return c.f;
}
static __device__ __forceinline__ float bfhi(unsigned u){
    union{unsigned x; float f;} c; c.x = u & 0xFFFF0000u; return c.f;
}
static __device__ __forceinline__ float rdlanef(float v, int l){
    return __int_as_float(__builtin_amdgcn_readlane(__float_as_int(v), l));
}
static __device__ __forceinline__ unsigned short f2bfu(float v){
    bf16 b = __float2bfloat16(v);
    union{bf16 b; unsigned short u;} c; c.b = b; return c.u;
}
static __device__ __forceinline__ int clampn(int v){ return ((unsigned)v >= NN) ? 0 : v; }

// ---------------- fused prep+bcount: dtype detect + weight transpose + per-block bucket hist ----------------
// 1024 blocks (4/CU): edge histogram gets 4x the latency-hiding of the old 256-block shape.
// No global bcounts atomics: totals computed by k_rowsum from bh.
__global__ __launch_bounds__(256) void k_prepcount(const unsigned short* __restrict__ featu,
                                                   const void* __restrict__ W1, const void* __restrict__ W2,
                                                   const void* __restrict__ W3, const int* __restrict__ dst,
                                                   int* __restrict__ dflag, int* __restrict__ bh,
                                                   unsigned short* __restrict__ wtg){
    __shared__ int cnt;
    __shared__ int hist[NB];
    const int t = threadIdx.x, b = blockIdx.x;
    if (t == 0) cnt = 0;
    for (int i = t; i < NB; i += 256) hist[i] = 0;
    __syncthreads();
    unsigned short lo = featu[2 * t];
    int e = (lo >> 7) & 0xFF;
    if (e >= 117 && e <= 137) atomicAdd(&cnt, 1);
    __syncthreads();
    const int isbf = (cnt >= 128) ? 1 : 0;   // 1 => bf16 inputs
    int idx = b * 256 + t;
    if (idx == 0) *dflag = isbf;
    if (idx < 32768){
        int l = idx >> 14;                   // 0: W1, 1: W2
        int e2 = idx & 16383;
        int f = e2 >> 7, k = e2 & 127;
        const void* W = l ? W2 : W1;
        wtg[idx] = f2bfu(ldf(W, k * FF + f, isbf));
    } else if (idx < 34816){
        int e2 = idx - 32768;                // W3t: 16x128
        int f = e2 >> 7, k = e2 & 127;
        wtg[idx] = f2bfu(ldf(W3, k * CC + f, isbf));
    }
    // bucket histogram of this block's edge partition (int4: 4 edges per load)
    const int beg = b * CH;
    const int end = (beg + CH < NE) ? beg + CH : NE;
    if (end > beg){
        const int4* d4 = (const int4*)(dst + beg);
        const int n4 = (end - beg) >> 2;     // CH multiple of 4
        for (int i = t; i < n4; i += 256){
            int4 d = d4[i];
            atomicAdd(&hist[clampn(d.x) >> 6], 1);
            atomicAdd(&hist[clampn(d.y) >> 6], 1);
            atomicAdd(&hist[clampn(d.z) >> 6], 1);
            atomicAdd(&hist[clampn(d.w) >> 6], 1);
        }
    }
    __syncthreads();
    for (int k = t; k < NB; k += 256) bh[k * NBLK + b] = hist[k];
}

// ---------------- rowsum: bucket totals from bh (wave-per-bucket, int4). Replaces memset+atomics. ----------------
__global__ __launch_bounds__(256) void k_rowsum(const int* __restrict__ bh, int* __restrict__ bcounts){
    int k = blockIdx.x * 4 + (threadIdx.x >> 6);
    int lane = threadIdx.x & 63;
    if (k >= NB) return;
    const int4* row = (const int4*)(bh + k * NBLK);   // 256 int4 per row
    int s = 0;
    #pragma unroll
    for (int i = 0; i < 4; i++){
        int4 v = row[lane * 4 + i];
        s += v.x + v.y + v.z + v.w;
    }
    #pragma unroll
    for (int off = 32; off; off >>= 1) s += __shfl_xor(s, off);
    if (lane == 0) bcounts[k] = s;
}

// ---------------- bscan: exclusive scan of bucket totals -> bbase ----------------
__global__ __launch_bounds__(256) void k_bscan(const int* __restrict__ bcounts, int* __restrict__ bbase,
                                               int* __restrict__ rowptr){
    __shared__ int s[256];
    const int t = threadIdx.x;
    constexpr int PT = (NB + 255) / 256;   // 4
    int loc[PT];
    int sum = 0;
    #pragma unroll
    for (int i = 0; i < PT; i++){
        int idx = t * PT + i;
        int v = (idx < NB) ? bcounts[idx] : 0;
        loc[i] = sum;
        sum += v;
    }
    s[t] = sum; __syncthreads();
    for (int off = 1; off < 256; off <<= 1){
        int x = (t >= off) ? s[t - off] : 0;
        __syncthreads();
        s[t] += x;
        __syncthreads();
    }
    int base = (t > 0) ? s[t - 1] : 0;
    #pragma unroll
    for (int i = 0; i < PT; i++){
        int idx = t * PT + i;
        if (idx < NB) bbase[idx] = base + loc[i];
    }
    if (t == 255){
        bbase[NB] = s[255];      // == NE
        rowptr[NN] = s[255];
    }
}

// Per-bucket offsets: wave-per-bucket shfl scan over the 1024 per-block counts (16/lane).
__global__ __launch_bounds__(256) void k_boffset(const int* __restrict__ bbase, int* __restrict__ bh){
    int k = blockIdx.x * 4 + (threadIdx.x >> 6);
    int lane = threadIdx.x & 63;
    if (k >= NB) return;
    int v[16];
    int s = 0;
    #pragma unroll
    for (int i = 0; i < 16; i++){
        v[i] = bh[k * NBLK + 16 * lane + i];
        s += v[i];
    }
    int tot = s;
    #pragma unroll
    for (int off = 1; off < 64; off <<= 1){
        int x = __shfl_up(s, off);
        if (lane >= off) s += x;
    }
    int run = bbase[k] + s - tot;   // exclusive prefix of per-lane sums
    #pragma unroll
    for (int i = 0; i < 16; i++){
        bh[k * NBLK + 16 * lane + i] = run;
        run += v[i];
    }
}

// ---------------- FAT kernel: bucket-scatter (blocks 0..1023) || layer-1 MFMA GEMM (blocks 1024..1805) ----------------
// Bucket role: 1024 blocks (4/CU) reading src/dst as int4.

__global__ __launch_bounds__(256) void k_fat(const int* __restrict__ src, const int* __restrict__ dst,
                                             const int* __restrict__ bh, unsigned* __restrict__ bpairs,
                                             const void* __restrict__ X, const unsigned short* __restrict__ wtg,
                                             const void* __restrict__ al, const void* __restrict__ ar,
                                             const int* __restrict__ dflag, bf16* __restrict__ ft,
                                             float* __restrict__ el, float* __restrict__ er){
    if (blockIdx.x < NBLK){
        // ---- bucket role ----
        __shared__ int cur[NB];
        const int t = threadIdx.x, b = blockIdx.x;
        for (int k = t; k < NB; k += 256) cur[k] = bh[k * NBLK + b];
        __syncthreads();
        const int beg = b * CH;
        const int end = (beg + CH < NE) ? beg + CH : NE;
        if (end > beg){
            const int4* s4 = (const int4*)(src + beg);
            const int4* d4 = (const int4*)(dst + beg);
            const int n4 = (end - beg) >> 2;
            for (int i = t; i < n4; i += 256){
                int4 sv = s4[i];
                int4 dv = d4[i];
                int ss, dd, p;
                ss = clampn(sv.x); dd = clampn(dv.x);
                p = atomicAdd(&cur[dd >> 6], 1);
                if ((unsigned)p < NE) bpairs[p] = (unsigned)ss | ((unsigned)(dd & 63) << 16);
                ss = clampn(sv.y); dd = clampn(dv.y);
                p = atomicAdd(&cur[dd >> 6], 1);
                if ((unsigned)p < NE) bpairs[p] = (unsigned)ss | ((unsigned)(dd & 63) << 16);
                ss = clampn(sv.z); dd = clampn(dv.z);
                p = atomicAdd(&cur[dd >> 6], 1);
                if ((unsigned)p < NE) bpairs[p] = (unsigned)ss | ((unsigned)(dd & 63) << 16);
                ss = clampn(sv.w); dd = clampn(dv.w);
                p = atomicAdd(&cur[dd >> 6], 1);
                if ((unsigned)p < NE) bpairs[p] = (unsigned)ss | ((unsigned)(dd & 63) << 16);
            }
        }
        return;
    }
    // ---- mgemm layer-1 role ----
    const int isbf = *dflag;
    const int t  = threadIdx.x;
    const int n0 = (blockIdx.x - NBLK) * 64;
    const int wv = t >> 6;
    const int lane = t & 63;
    const int quad = lane >> 4;
    const int mcol = lane & 15;
    const int row = n0 + wv * 16 + mcol;
    const int rc  = (row < NN) ? row : 0;   // clamped A row

    bf16x8 afr[4];
    if (!isbf){
        const float* xr = (const float*)X + rc * FF + quad * 8;
        #pragma unroll
        for (int kt = 0; kt < 4; kt++){
            float4 a = *(const float4*)(xr + kt * 32);
            float4 b = *(const float4*)(xr + kt * 32 + 4);
            union { bf16x8 v; unsigned u[4]; } c;
            c.u[0] = (unsigned)f2bfu(a.x) | ((unsigned)f2bfu(a.y) << 16);
            c.u[1] = (unsigned)f2bfu(a.z) | ((unsigned)f2bfu(a.w) << 16);
            c.u[2] = (unsigned)f2bfu(b.x) | ((unsigned)f2bfu(b.y) << 16);
            c.u[3] = (unsigned)f2bfu(b.z) | ((unsigned)f2bfu(b.w) << 16);
            afr[kt] = c.v;
        }
    } else {
        const unsigned short* xr = (const unsigned short*)X + rc * FF + quad * 8;
        #pragma unroll
        for (int kt = 0; kt < 4; kt++)
            afr[kt] = *(const bf16x8*)(xr + kt * 32);
    }

    float elp[4] = {0.f,0.f,0.f,0.f}, erp[4] = {0.f,0.f,0.f,0.f};

    #pragma unroll
    for (int f = 0; f < 8; f++){
        f32x4 acc = {0.f, 0.f, 0.f, 0.f};
        const unsigned short* wr = wtg + (f * 16 + mcol) * FF + quad * 8;
        #pragma unroll
        for (int kt = 0; kt < 4; kt++){
            bf16x8 bfr = *(const bf16x8*)(wr + kt * 32);
            acc = __builtin_amdgcn_mfma_f32_16x16x32_bf16(afr[kt], bfr, acc, 0, 0, 0);
        }
        int col = f * 16 + mcol;
        float alv = ldf(al, col, isbf);
        float arv = ldf(ar, col, isbf);
        #pragma unroll
        for (int reg = 0; reg < 4; reg++){
            int node = n0 + wv * 16 + quad * 4 + reg;
            float v = acc[reg];
            if (node < NN) ft[node * FF + col] = __float2bfloat16(v);
            elp[reg] += v * alv;
            erp[reg] += v * arv;
        }
    }

    #pragma unroll
    for (int reg = 0; reg < 4; reg++){
        float pl = elp[reg], pr = erp[reg];
        #pragma unroll
        for (int off = 1; off < 16; off <<= 1){
            pl += __shfl_xor(pl, off);
            pr += __shfl_xor(pr, off);
        }
        int node = n0 + wv * 16 + quad * 4 + reg;
        if (mcol == 0 && node < NN){ el[node] = pl; er[node] = pr; }
    }
}

// ---------------- bsort: in-bucket counting sort with LDS edge cache (no global re-read) ----------------

__global__ __launch_bounds__(256) void k_bsort(const unsigned* __restrict__ bpairs, const int* __restrict__ bbase,
                                               int* __restrict__ rowptr, int* __restrict__ csrsrc){
    __shared__ int cnt[64];
    __shared__ int cur[64];
    __shared__ unsigned ebuf[EBUF];   // 16KB: bucket avg 2048 edges, max ~2400 << 4096
    const int t = threadIdx.x;
    const int b = blockIdx.x;
    const int base = bbase[b];
    const int endb = bbase[b + 1];
    if (t < 64) cnt[t] = 0;
    __syncthreads();
    for (int i = base + t; i < endb; i += 256){
        unsigned pr = bpairs[i];
        int k = i - base;
        if (k < EBUF) ebuf[k] = pr;
        atomicAdd(&cnt[pr >> 16], 1);
    }
    __syncthreads();
    if (t < 64){   // wave 0 exactly: 64-lane exclusive scan via shfl
        int v = cnt[t];
        int inc = v;
        #pragma unroll
        for (int off = 1; off < 64; off <<= 1){
            int x = __shfl_up(inc, off);
            if (t >= off) inc += x;
        }
        int excl = inc - v;
        cur[t] = excl;
        int d = b * 64 + t;
        if (d < NN) rowptr[d] = base + excl;
    }
    __syncthreads();
    for (int i = base + t; i < endb; i += 256){
        int k = i - base;
        unsigned pr = (k < EBUF) ? ebuf[k] : bpairs[i];
        int p = atomicAdd(&cur[pr >> 16], 1);
        csrsrc[base + p] = (int)(pr & 0xFFFFu);
    }
}

// ---------------- MFMA GEMM (layer 2), LDS-FREE: hB(bf16) @ W2 ----------------

__global__ __launch_bounds__(256) void k_mgemm2(const void* __restrict__ X, const unsigned short* __restrict__ wtg,
                                                const void* __restrict__ al, const void* __restrict__ ar,
                                                const int* __restrict__ dflag, bf16* __restrict__ ft,
                                                float* __restrict__ el, float* __restrict__ er){
    const int isbf = *dflag;
    const int t  = threadIdx.x;
    const int n0 = blockIdx.x * 64;
    const int wv = t >> 6;
    const int lane = t & 63;
    const int quad = lane >> 4;
    const int mcol = lane & 15;
    const int row = n0 + wv * 16 + mcol;
    const int rc  = (row < NN) ? row : 0;

    bf16x8 afr[4];
    const unsigned short* xr = (const unsigned short*)X + rc * FF + quad * 8;
    #pragma unroll
    for (int kt = 0; kt < 4; kt++)
        afr[kt] = *(const bf16x8*)(xr + kt * 32);

    float elp[4] = {0.f,0.f,0.f,0.f}, erp[4] = {0.f,0.f,0.f,0.f};

    #pragma unroll
    for (int f = 0; f < 8; f++){
        f32x4 acc = {0.f, 0.f, 0.f, 0.f};
        const unsigned short* wr = wtg + (f * 16 + mcol) * FF + quad * 8;
        #pragma unroll
        for (int kt = 0; kt < 4; kt++){
            bf16x8 bfr = *(const bf16x8*)(wr + kt * 32);
            acc = __builtin_amdgcn_mfma_f32_16x16x32_bf16(afr[kt], bfr, acc, 0, 0, 0);
        }
        int col = f * 16 + mcol;
        float alv = ldf(al, col, isbf);
        float arv = ldf(ar, col, isbf);
        #pragma unroll
        for (int reg = 0; reg < 4; reg++){
            int node = n0 + wv * 16 + quad * 4 + reg;
            float v = acc[reg];
            if (node < NN) ft[node * FF + col] = __float2bfloat16(v);
            elp[reg] += v * alv;
            erp[reg] += v * arv;
        }
    }

    #pragma unroll
    for (int reg = 0; reg < 4; reg++){
        float pl = elp[reg], pr = erp[reg];
        #pragma unroll
        for (int off = 1; off < 16; off <<= 1){
            pl += __shfl_xor(pl, off);
            pr += __shfl_xor(pr, off);
        }
        int node = n0 + wv * 16 + quad * 4 + reg;
        if (mcol == 0 && node < NN){ el[node] = pl; er[node] = pr; }
    }
}

// ---------------- MFMA GEMM (layer 3), LDS-FREE: ft3 = X(bf16) @ W3, f32 out ----------------

__global__ __launch_bounds__(256) void k_mgemm3(const void* __restrict__ X, const unsigned short* __restrict__ wt3g,
                                                const void* __restrict__ al, const void* __restrict__ ar,
                                                const int* __restrict__ dflag, float* __restrict__ ft,
                                                float* __restrict__ el, float* __restrict__ er){
    const int isbf = *dflag;
    const int t  = threadIdx.x;
    const int n0 = blockIdx.x * 64;
    const int wv = t >> 6;
    const int lane = t & 63;
    const int quad = lane >> 4;
    const int mcol = lane & 15;
    const int row = n0 + wv * 16 + mcol;
    const int rc  = (row < NN) ? row : 0;

    const unsigned short* xr = (const unsigned short*)X + rc * FF + quad * 8;
    const unsigned short* wr = wt3g + mcol * FF + quad * 8;

    f32x4 acc = {0.f, 0.f, 0.f, 0.f};
    #pragma unroll
    for (int kt = 0; kt < 4; kt++){
        bf16x8 afr = *(const bf16x8*)(xr + kt * 32);
        bf16x8 bfr = *(const bf16x8*)(wr + kt * 32);
        acc = __builtin_amdgcn_mfma_f32_16x16x32_bf16(afr, bfr, acc, 0, 0, 0);
    }

    float alv = ldf(al, mcol, isbf);
    float arv = ldf(ar, mcol, isbf);
    #pragma unroll
    for (int reg = 0; reg < 4; reg++){
        int node = n0 + wv * 16 + quad * 4 + reg;
        float v = acc[reg];
        if (node < NN) ft[node * CC + mcol] = v;
        float pl = v * alv, pr = v * arv;
        #pragma unroll
        for (int off = 1; off < 16; off <<= 1){
            pl += __shfl_xor(pl, off);
            pr += __shfl_xor(pr, off);
        }
        if (mcol == 0 && node < NN){ el[node] = pl; er[node] = pr; }
    }
}

// ---------------- Aggregation (128 feats, bf16 ft): round-0 proven kernel, bf16 output ----------------

__global__ __launch_bounds__(256) void k_agg128(const void* __restrict__ ftv, const float* __restrict__ el,
                                                const float* __restrict__ er, const int* __restrict__ rowptr,
                                                const int* __restrict__ csrsrc, const void* __restrict__ bias,
                                                const int* __restrict__ dflag, unsigned* __restrict__ outp){
    const int isbf = *dflag;
    int lane = threadIdx.x & 63;
    int n = blockIdx.x * 4 + (threadIdx.x >> 6);
    if (n >= NN) return;
    int beg = rowptr[n], end = rowptr[n + 1];
    beg = (beg < 0) ? 0 : (beg > NE ? NE : beg);
    end = (end < beg) ? beg : (end > NE ? NE : end);
    int deg = end - beg;
    float erd = er[n];

    float m = -3.4e38f;
    int   s_c = 0;
    float e_c = 0.f;
    for (int i = beg + lane; i < end; i += 64){
        int s = csrsrc[i];
        if ((unsigned)s >= NN) s = 0;
        float e = el[s] + erd;
        e = (e >= 0.f) ? e : 0.2f * e;
        if (i < beg + 64){ s_c = s; e_c = e; }
        m = fmaxf(m, e);
    }
    #pragma unroll
    for (int off = 32; off; off >>= 1) m = fmaxf(m, __shfl_xor(m, off));

    int jmax = (deg < 64) ? deg : 64;
    float w_c = (lane < jmax) ? __expf(e_c - m) : 0.f;
    float lsum = w_c;
    #pragma unroll
    for (int off = 32; off; off >>= 1) lsum += __shfl_xor(lsum, off);

    const unsigned* ftb = (const unsigned*)ftv;
    float acc0 = 0.f, acc1 = 0.f;
    int j = 0;
    if (jmax >= 8){
        float w[8]; unsigned u[8];
        #pragma unroll
        for (int q = 0; q < 8; q++){
            int s = __builtin_amdgcn_readlane(s_c, q);
            w[q] = rdlanef(w_c, q);
            u[q] = (ftb + s * 64)[lane];
        }
        for (j = 8; j + 8 <= jmax; j += 8){
            float wn[8]; unsigned un[8];
            #pragma unroll
            for (int q = 0; q < 8; q++){
                int s = __builtin_amdgcn_readlane(s_c, j + q);
                wn[q] = rdlanef(w_c, j + q);
                un[q] = (ftb + s * 64)[lane];
            }
            #pragma unroll
            for (int q = 0; q < 8; q++){
                acc0 += w[q] * bflo(u[q]);
                acc1 += w[q] * bfhi(u[q]);
                w[q] = wn[q]; u[q] = un[q];
            }
        }
        #pragma unroll
        for (int q = 0; q < 8; q++){
            acc0 += w[q] * bflo(u[q]);
            acc1 += w[q] * bfhi(u[q]);
        }
    }
    for (; j < jmax; ++j){
        int s = __builtin_amdgcn_readlane(s_c, j);
        float w = rdlanef(w_c, j);
        unsigned u = (ftb + s * 64)[lane];
        acc0 += w * bflo(u); acc1 += w * bfhi(u);
    }
    for (int i = beg + 64; i < end; ++i){
        int s = csrsrc[i];
        if ((unsigned)s >= NN) s = 0;
        float e = el[s] + erd;
        e = (e >= 0.f) ? e : 0.2f * e;
        float w = __expf(e - m);
        unsigned u = (ftb + s * 64)[lane];
        lsum += w;
        acc0 += w * bflo(u); acc1 += w * bfhi(u);
    }
    float inv = 1.f / ((lsum > 0.f) ? lsum : 1.f);
    float o0 = fmaxf(acc0 * inv + ldf(bias, 2 * lane,     isbf), 0.f);
    float o1 = fmaxf(acc1 * inv + ldf(bias, 2 * lane + 1, isbf), 0.f);
    unsigned pk = (unsigned)f2bfu(o0) | ((unsigned)f2bfu(o1) << 16);
    outp[n * 64 + lane] = pk;
}

// ---------------- Aggregation (16 feats, f32 ft): single-pass gather with inline softmax ----------------

__global__ __launch_bounds__(256) void k_agg16(const float* __restrict__ ftv, const float* __restrict__ el,
                                               const float* __restrict__ er, const int* __restrict__ rowptr,
                                               const int* __restrict__ csrsrc, const void* __restrict__ bias,
                                               const int* __restrict__ dflag, void* __restrict__ outp){
    const int isbf = *dflag;
    const int lane = threadIdx.x & 63;
    const int n = blockIdx.x * 4 + (threadIdx.x >> 6);
    if (n >= NN) return;
    int beg = rowptr[n], end = rowptr[n + 1];
    beg = (beg < 0) ? 0 : (beg > NE ? NE : beg);
    end = (end < beg) ? beg : (end > NE ? NE : end);
    const float erd = er[n];

    const int g = lane >> 2;     // edge slot 0..15
    const int c = lane & 3;      // float4 index within 64B row
    const float4* ftq = (const float4*)ftv;
    float a0 = 0.f, a1 = 0.f, a2 = 0.f, a3 = 0.f;
    float lsum = 0.f;

    for (int j = beg; j < end; j += 32){
        #pragma unroll
        for (int q = 0; q < 2; q++){
            int iq = j + q * 16 + g;
            int cq = (iq < end) ? iq : beg;
            int s  = csrsrc[cq];
            if ((unsigned)s >= NN) s = 0;
            float e = el[s] + erd;
            e = (e >= 0.f) ? e : 0.2f * e;
            float w = (iq < end) ? __expf(e) : 0.f;
            float4 u = ftq[(unsigned)s * 4u + c];
            lsum += w;
            a0 += w * u.x; a1 += w * u.y; a2 += w * u.z; a3 += w * u.w;
        }
    }

    // Sum across the 16 groups (lane bits 2-5).
    #pragma unroll
    for (int off = 4; off < 64; off <<= 1){
        a0 += __shfl_xor(a0, off);
        a1 += __shfl_xor(a1, off);
        a2 += __shfl_xor(a2, off);
        a3 += __shfl_xor(a3, off);
        lsum += __shfl_xor(lsum, off);
    }

    if (lane < 4){
        float inv = (lsum > 0.f) ? 1.f / lsum : 0.f;
        float o0 = fmaxf(a0 * inv + ldf(bias, c * 4 + 0, isbf), 0.f);
        float o1 = fmaxf(a1 * inv + ldf(bias, c * 4 + 1, isbf), 0.f);
        float o2 = fmaxf(a2 * inv + ldf(bias, c * 4 + 2, isbf), 0.f);
        float o3 = fmaxf(a3 * inv + ldf(bias, c * 4 + 3, isbf), 0.f);
        if (isbf){
            uint2 pk;
            pk.x = (unsigned)f2bfu(o0) | ((unsigned)f2bfu(o1) << 16);
            pk.y = (unsigned)f2bfu(o2) | ((unsigned)f2bfu(o3) << 16);
            ((uint2*)outp)[n * 4 + c] = pk;
        } else {
            float4 o; o.x = o0; o.y = o1; o.z = o2; o.w = o3;
            ((float4*)outp)[n * 4 + c] = o;
        }
    }
}

// ---------------- host launch ----------------

static size_t align256(size_t x){ return (x + 255) & ~(size_t)255; }

extern "C" void kernel_launch(void* const* d_in, const int* in_sizes, int n_in,
                              void* d_out, int out_size, void* d_ws, size_t ws_size,
                              hipStream_t stream) {
    const void* feat = d_in[0];
    const int*  src  = (const int*)d_in[1];
    const int*  dst  = (const int*)d_in[2];
    const void* W1 = d_in[3];
    const void* al1= d_in[4];
    const void* ar1= d_in[5];
    const void* b1 = d_in[6];
    const void* W2 = d_in[7];
    const void* al2= d_in[8];
    const void* ar2= d_in[9];
    const void* b2 = d_in[10];
    const void* W3 = d_in[11];
    const void* al3= d_in[12];
    const void* ar3= d_in[13];
    const void* b3 = d_in[14];

    // workspace carve
    char* p = (char*)d_ws;
    size_t off = 0;
    auto carve = [&](size_t bytes)->void*{
        void* r = p + off;
        off += align256(bytes);
        return r;
    };
    float* ftA   = (float*)carve((size_t)NN * FF * 4);   // ft buffer: bf16 view (layers 1/2), f32 view (layer 3)
    unsigned* hB = (unsigned*)carve((size_t)NN * FF * 4); // hidden state bf16-packed; bpairs overlays pre-layer-1
    float* el    = (float*)carve((size_t)NN * 4);
    float* er    = (float*)carve((size_t)NN * 4);
    int*   rowptr= (int*)  carve((size_t)(NN + 1) * 4);
    int*   csrsrc= (int*)  carve((size_t)NE * 4);
    int*   bcounts=(int*)  carve((size_t)NB * 4);
    int*   bbase  =(int*)  carve((size_t)(NB + 1) * 4);
    int*   bh     =(int*)  carve((size_t)NB * NBLK * 4);  // per-(bucket,block) hist/offsets, 3.2MB
    unsigned short* wtg = (unsigned short*)carve((size_t)34816 * 2);  // W1t,W2t,W3t bf16
    int*   dflag  =(int*)  carve(256);
    unsigned* bpairs = (unsigned*)hB;   // overlay: consumed (k_bsort) before hB is first written (agg128-1)
    void*  ftb   = ftA;                 // bf16 ft view (layers 1-2); f32 ft3 view (layer 3)
    (void)ws_size; (void)n_in; (void)in_sizes; (void)out_size;

    dim3 b256(256);
    const int mg_grid   = (NN + 63) / 64;     // 782
    const int node_grid = (NN + 3) / 4;       // 12500

    // 1: fused prep+bcount (dtype detect, weight transpose, per-block hist; 1024 blocks)
    k_prepcount<<<dim3(NBLK), b256, 0, stream>>>((const unsigned short*)feat, W1, W2, W3, dst,
                                                 dflag, bh, wtg);
    // 2: bucket totals from bh (replaces memset + global atomics)
    k_rowsum<<<dim3((NB + 3) / 4), b256, 0, stream>>>(bh, bcounts);
    // 3: exclusive scan of bucket totals
    k_bscan<<<dim3(1), b256, 0, stream>>>(bcounts, bbase, rowptr);
    // 4: per-(bucket,block) offsets (16/lane scan over 1024 counts)
    k_boffset<<<dim3((NB + 3) / 4), b256, 0, stream>>>(bbase, bh);
    // 5: FAT — bucket scatter (1024 blocks, 4/CU) || layer-1 GEMM (782 blocks)
    k_fat<<<dim3(NBLK + mg_grid), b256, 0, stream>>>(src, dst, bh, bpairs, feat, wtg, al1, ar1,
                                                     dflag, (bf16*)ftb, el, er);
    // 6: in-bucket counting sort with LDS edge cache -> rowptr, csrsrc
    k_bsort<<<dim3(NB), b256, 0, stream>>>(bpairs, bbase, rowptr, csrsrc);

    // 7: layer-1 aggregation -> hB (bf16-packed)
    k_agg128<<<dim3(node_grid), b256, 0, stream>>>(ftb, el, er, rowptr, csrsrc, b1, dflag, hB);
    // 8-9: layer 2
    k_mgemm2<<<dim3(mg_grid), b256, 0, stream>>>(hB, wtg + 16384, al2, ar2, dflag, (bf16*)ftb, el, er);
    k_agg128<<<dim3(node_grid), b256, 0, stream>>>(ftb, el, er, rowptr, csrsrc, b2, dflag, hB);
    // 10-11: layer 3
    k_mgemm3<<<dim3(mg_grid), b256, 0, stream>>>(hB, wtg + 32768, al3, ar3, dflag, (float*)ftb, el, er);
    k_agg16<<<dim3(node_grid), b256, 0, stream>>>((const float*)ftb, el, er, rowptr, csrsrc, b3, dflag, d_out);
}

// Round 11
// 314.331 us; speedup vs baseline: 1.0668x; 1.0668x over previous
//
#include <hip/hip_runtime.h>
#include <hip/hip_bf16.h>

#define NN 50000
#define NE 1600000
#define FF 128
#define CC 16
#define NB ((NN + 63) / 64)       // 782 dst-buckets of 64 nodes
#define NBLK 256                  // partition blocks for the sort (R9-proven shape)
#define CH 6400                   // edges per partition block (16B-aligned; blocks 250..255 idle)
#define EBUF 4096                 // bsort LDS edge cache (16KB; bucket avg 2048, max ~2400)

using bf16 = __hip_bfloat16;
using bf16x8 = __attribute__((ext_vector_type(8))) short;   // 8 bf16 = 4 VGPRs
using f32x4  = __attribute__((ext_vector_type(4))) float;

// Runtime-dtype load: isbf selects bf16 vs f32 interpretation of p.
static __device__ __forceinline__ float ldf(const void* p, int i, int isbf){
    return isbf ? __bfloat162float(((const bf16*)p)[i]) : ((const float*)p)[i];
}
static __device__ __forceinline__ float bflo(unsigned u){
    union{unsigned x; float f;} c; c.x = u << 16; return c.f;
}
static __device__ __forceinline__ float bfhi(unsigned u){
    union{unsigned x; float f;} c; c.x = u & 0xFFFF0000u; return c.f;
}
static __device__ __forceinline__ float rdlanef(float v, int l){
    return __int_as_float(__builtin_amdgcn_readlane(__float_as_int(v), l));
}
static __device__ __forceinline__ unsigned short f2bfu(float v){
    bf16 b = __float2bfloat16(v);
    union{bf16 b; unsigned short u;} c; c.b = b; return c.u;
}
static __device__ __forceinline__ int clampn(int v){ return ((unsigned)v >= NN) ? 0 : v; }

// ---------------- fused prep+bcount: dtype detect + weight transpose + per-block bucket hist ----------------
// bcounts zeroed by hipMemsetAsync; totals accumulated via atomics. dst stream read as int4 (4 edges/load).
__global__ __launch_bounds__(256) void k_prepcount(const unsigned short* __restrict__ featu,
                                                   const void* __restrict__ W1, const void* __restrict__ W2,
                                                   const void* __restrict__ W3, const int* __restrict__ dst,
                                                   int* __restrict__ dflag, int* __restrict__ bh,
                                                   int* __restrict__ bcounts, unsigned short* __restrict__ wtg){
    __shared__ int cnt;
    __shared__ int hist[NB];
    const int t = threadIdx.x, b = blockIdx.x;
    if (t == 0) cnt = 0;
    for (int i = t; i < NB; i += 256) hist[i] = 0;
    __syncthreads();
    unsigned short lo = featu[2 * t];
    int e = (lo >> 7) & 0xFF;
    if (e >= 117 && e <= 137) atomicAdd(&cnt, 1);
    __syncthreads();
    const int isbf = (cnt >= 128) ? 1 : 0;   // 1 => bf16 inputs
    int idx = b * 256 + t;
    if (idx == 0) *dflag = isbf;
    if (idx < 32768){
        int l = idx >> 14;                   // 0: W1, 1: W2
        int e2 = idx & 16383;
        int f = e2 >> 7, k = e2 & 127;
        const void* W = l ? W2 : W1;
        wtg[idx] = f2bfu(ldf(W, k * FF + f, isbf));
    } else if (idx < 34816){
        int e2 = idx - 32768;                // W3t: 16x128
        int f = e2 >> 7, k = e2 & 127;
        wtg[idx] = f2bfu(ldf(W3, k * CC + f, isbf));
    }
    // bucket histogram of this block's edge partition (int4: 4 edges per load)
    const int beg = b * CH;
    const int end = (beg + CH < NE) ? beg + CH : NE;
    if (end > beg){
        const int4* d4 = (const int4*)(dst + beg);
        const int n4 = (end - beg) >> 2;     // CH and NE both multiples of 4
        for (int i = t; i < n4; i += 256){
            int4 d = d4[i];
            atomicAdd(&hist[clampn(d.x) >> 6], 1);
            atomicAdd(&hist[clampn(d.y) >> 6], 1);
            atomicAdd(&hist[clampn(d.z) >> 6], 1);
            atomicAdd(&hist[clampn(d.w) >> 6], 1);
        }
    }
    __syncthreads();
    for (int k = t; k < NB; k += 256){
        int v = hist[k];
        bh[k * NBLK + b] = v;
        if (v) atomicAdd(&bcounts[k], v);
    }
}

// ---------------- bscan: exclusive scan of bucket totals -> bbase ----------------
__global__ __launch_bounds__(256) void k_bscan(const int* __restrict__ bcounts, int* __restrict__ bbase,
                                               int* __restrict__ rowptr){
    __shared__ int s[256];
    const int t = threadIdx.x;
    constexpr int PT = (NB + 255) / 256;   // 4
    int loc[PT];
    int sum = 0;
    #pragma unroll
    for (int i = 0; i < PT; i++){
        int idx = t * PT + i;
        int v = (idx < NB) ? bcounts[idx] : 0;
        loc[i] = sum;
        sum += v;
    }
    s[t] = sum; __syncthreads();
    for (int off = 1; off < 256; off <<= 1){
        int x = (t >= off) ? s[t - off] : 0;
        __syncthreads();
        s[t] += x;
        __syncthreads();
    }
    int base = (t > 0) ? s[t - 1] : 0;
    #pragma unroll
    for (int i = 0; i < PT; i++){
        int idx = t * PT + i;
        if (idx < NB) bbase[idx] = base + loc[i];
    }
    if (t == 255){
        bbase[NB] = s[255];      // == NE
        rowptr[NN] = s[255];
    }
}

// Per-bucket offsets: wave-per-bucket shfl scan over the 256 per-block counts (4/lane).
__global__ __launch_bounds__(256) void k_boffset(const int* __restrict__ bbase, int* __restrict__ bh){
    int k = blockIdx.x * 4 + (threadIdx.x >> 6);
    int lane = threadIdx.x & 63;
    if (k >= NB) return;
    int v[4];
    int s = 0;
    #pragma unroll
    for (int i = 0; i < 4; i++){
        v[i] = bh[k * NBLK + 4 * lane + i];
        s += v[i];
    }
    int tot = s;
    #pragma unroll
    for (int off = 1; off < 64; off <<= 1){
        int x = __shfl_up(s, off);
        if (lane >= off) s += x;
    }
    int run = bbase[k] + s - tot;   // exclusive prefix of per-lane sums
    #pragma unroll
    for (int i = 0; i < 4; i++){
        bh[k * NBLK + 4 * lane + i] = run;
        run += v[i];
    }
}

// ---------------- FAT kernel: bucket-scatter (blocks 0..255) || layer-1 MFMA GEMM (blocks 256..1037) ----------------
// Bucket role reads src/dst as int4 (4 edges per load per stream).

__global__ __launch_bounds__(256) void k_fat(const int* __restrict__ src, const int* __restrict__ dst,
                                             const int* __restrict__ bh, unsigned* __restrict__ bpairs,
                                             const void* __restrict__ X, const unsigned short* __restrict__ wtg,
                                             const void* __restrict__ al, const void* __restrict__ ar,
                                             const int* __restrict__ dflag, bf16* __restrict__ ft,
                                             float* __restrict__ el, float* __restrict__ er){
    if (blockIdx.x < NBLK){
        // ---- bucket role ----
        __shared__ int cur[NB];
        const int t = threadIdx.x, b = blockIdx.x;
        for (int k = t; k < NB; k += 256) cur[k] = bh[k * NBLK + b];
        __syncthreads();
        const int beg = b * CH;
        const int end = (beg + CH < NE) ? beg + CH : NE;
        if (end > beg){
            const int4* s4 = (const int4*)(src + beg);
            const int4* d4 = (const int4*)(dst + beg);
            const int n4 = (end - beg) >> 2;
            for (int i = t; i < n4; i += 256){
                int4 sv = s4[i];
                int4 dv = d4[i];
                int ss, dd, p;
                ss = clampn(sv.x); dd = clampn(dv.x);
                p = atomicAdd(&cur[dd >> 6], 1);
                if ((unsigned)p < NE) bpairs[p] = (unsigned)ss | ((unsigned)(dd & 63) << 16);
                ss = clampn(sv.y); dd = clampn(dv.y);
                p = atomicAdd(&cur[dd >> 6], 1);
                if ((unsigned)p < NE) bpairs[p] = (unsigned)ss | ((unsigned)(dd & 63) << 16);
                ss = clampn(sv.z); dd = clampn(dv.z);
                p = atomicAdd(&cur[dd >> 6], 1);
                if ((unsigned)p < NE) bpairs[p] = (unsigned)ss | ((unsigned)(dd & 63) << 16);
                ss = clampn(sv.w); dd = clampn(dv.w);
                p = atomicAdd(&cur[dd >> 6], 1);
                if ((unsigned)p < NE) bpairs[p] = (unsigned)ss | ((unsigned)(dd & 63) << 16);
            }
        }
        return;
    }
    // ---- mgemm layer-1 role ----
    const int isbf = *dflag;
    const int t  = threadIdx.x;
    const int n0 = (blockIdx.x - NBLK) * 64;
    const int wv = t >> 6;
    const int lane = t & 63;
    const int quad = lane >> 4;
    const int mcol = lane & 15;
    const int row = n0 + wv * 16 + mcol;
    const int rc  = (row < NN) ? row : 0;   // clamped A row

    bf16x8 afr[4];
    if (!isbf){
        const float* xr = (const float*)X + rc * FF + quad * 8;
        #pragma unroll
        for (int kt = 0; kt < 4; kt++){
            float4 a = *(const float4*)(xr + kt * 32);
            float4 b = *(const float4*)(xr + kt * 32 + 4);
            union { bf16x8 v; unsigned u[4]; } c;
            c.u[0] = (unsigned)f2bfu(a.x) | ((unsigned)f2bfu(a.y) << 16);
            c.u[1] = (unsigned)f2bfu(a.z) | ((unsigned)f2bfu(a.w) << 16);
            c.u[2] = (unsigned)f2bfu(b.x) | ((unsigned)f2bfu(b.y) << 16);
            c.u[3] = (unsigned)f2bfu(b.z) | ((unsigned)f2bfu(b.w) << 16);
            afr[kt] = c.v;
        }
    } else {
        const unsigned short* xr = (const unsigned short*)X + rc * FF + quad * 8;
        #pragma unroll
        for (int kt = 0; kt < 4; kt++)
            afr[kt] = *(const bf16x8*)(xr + kt * 32);
    }

    float elp[4] = {0.f,0.f,0.f,0.f}, erp[4] = {0.f,0.f,0.f,0.f};

    #pragma unroll
    for (int f = 0; f < 8; f++){
        f32x4 acc = {0.f, 0.f, 0.f, 0.f};
        const unsigned short* wr = wtg + (f * 16 + mcol) * FF + quad * 8;
        #pragma unroll
        for (int kt = 0; kt < 4; kt++){
            bf16x8 bfr = *(const bf16x8*)(wr + kt * 32);
            acc = __builtin_amdgcn_mfma_f32_16x16x32_bf16(afr[kt], bfr, acc, 0, 0, 0);
        }
        int col = f * 16 + mcol;
        float alv = ldf(al, col, isbf);
        float arv = ldf(ar, col, isbf);
        #pragma unroll
        for (int reg = 0; reg < 4; reg++){
            int node = n0 + wv * 16 + quad * 4 + reg;
            float v = acc[reg];
            if (node < NN) ft[node * FF + col] = __float2bfloat16(v);
            elp[reg] += v * alv;
            erp[reg] += v * arv;
        }
    }

    #pragma unroll
    for (int reg = 0; reg < 4; reg++){
        float pl = elp[reg], pr = erp[reg];
        #pragma unroll
        for (int off = 1; off < 16; off <<= 1){
            pl += __shfl_xor(pl, off);
            pr += __shfl_xor(pr, off);
        }
        int node = n0 + wv * 16 + quad * 4 + reg;
        if (mcol == 0 && node < NN){ el[node] = pl; er[node] = pr; }
    }
}

// ---------------- bsort: in-bucket counting sort, LDS permute -> fully coalesced csrsrc writes ----------------
// The scatter permutation happens in LDS (obuf, 16-bit src values: src < 50000 < 65536), then the
// sorted run streams out linearly — consecutive threads write consecutive addresses (full lines),
// replacing R9's scattered 4B global writes (R6 showed partial-line scatter costs up to 16x traffic).
// Fallback to direct global scatter if a bucket ever exceeds EBUF (never for this graph: max ~2400).

__global__ __launch_bounds__(256) void k_bsort(const unsigned* __restrict__ bpairs, const int* __restrict__ bbase,
                                               int* __restrict__ rowptr, int* __restrict__ csrsrc){
    __shared__ int cnt[64];
    __shared__ int cur[64];
    __shared__ unsigned ebuf[EBUF];          // 16KB input cache
    __shared__ unsigned short obuf[EBUF];    // 8KB sorted src values
    const int t = threadIdx.x;
    const int b = blockIdx.x;
    const int base = bbase[b];
    const int endb = bbase[b + 1];
    const int sz = endb - base;
    if (t < 64) cnt[t] = 0;
    __syncthreads();
    for (int i = base + t; i < endb; i += 256){
        unsigned pr = bpairs[i];
        int k = i - base;
        if (k < EBUF) ebuf[k] = pr;
        atomicAdd(&cnt[pr >> 16], 1);
    }
    __syncthreads();
    if (t < 64){   // wave 0 exactly: 64-lane exclusive scan via shfl
        int v = cnt[t];
        int inc = v;
        #pragma unroll
        for (int off = 1; off < 64; off <<= 1){
            int x = __shfl_up(inc, off);
            if (t >= off) inc += x;
        }
        int excl = inc - v;
        cur[t] = excl;
        int d = b * 64 + t;
        if (d < NN) rowptr[d] = base + excl;
    }
    __syncthreads();
    if (sz <= EBUF){
        // LDS permute, then coalesced stream-out.
        for (int k = t; k < sz; k += 256){
            unsigned pr = ebuf[k];
            int p = atomicAdd(&cur[pr >> 16], 1);
            obuf[p] = (unsigned short)(pr & 0xFFFFu);
        }
        __syncthreads();
        for (int k = t; k < sz; k += 256)
            csrsrc[base + k] = (int)obuf[k];
    } else {
        // Fallback: direct global scatter (R9 path).
        for (int i = base + t; i < endb; i += 256){
            int k = i - base;
            unsigned pr = (k < EBUF) ? ebuf[k] : bpairs[i];
            int p = atomicAdd(&cur[pr >> 16], 1);
            csrsrc[base + p] = (int)(pr & 0xFFFFu);
        }
    }
}

// ---------------- MFMA GEMM (layer 2), LDS-FREE: hB(bf16) @ W2 ----------------

__global__ __launch_bounds__(256) void k_mgemm2(const void* __restrict__ X, const unsigned short* __restrict__ wtg,
                                                const void* __restrict__ al, const void* __restrict__ ar,
                                                const int* __restrict__ dflag, bf16* __restrict__ ft,
                                                float* __restrict__ el, float* __restrict__ er){
    const int isbf = *dflag;
    const int t  = threadIdx.x;
    const int n0 = blockIdx.x * 64;
    const int wv = t >> 6;
    const int lane = t & 63;
    const int quad = lane >> 4;
    const int mcol = lane & 15;
    const int row = n0 + wv * 16 + mcol;
    const int rc  = (row < NN) ? row : 0;

    bf16x8 afr[4];
    const unsigned short* xr = (const unsigned short*)X + rc * FF + quad * 8;
    #pragma unroll
    for (int kt = 0; kt < 4; kt++)
        afr[kt] = *(const bf16x8*)(xr + kt * 32);

    float elp[4] = {0.f,0.f,0.f,0.f}, erp[4] = {0.f,0.f,0.f,0.f};

    #pragma unroll
    for (int f = 0; f < 8; f++){
        f32x4 acc = {0.f, 0.f, 0.f, 0.f};
        const unsigned short* wr = wtg + (f * 16 + mcol) * FF + quad * 8;
        #pragma unroll
        for (int kt = 0; kt < 4; kt++){
            bf16x8 bfr = *(const bf16x8*)(wr + kt * 32);
            acc = __builtin_amdgcn_mfma_f32_16x16x32_bf16(afr[kt], bfr, acc, 0, 0, 0);
        }
        int col = f * 16 + mcol;
        float alv = ldf(al, col, isbf);
        float arv = ldf(ar, col, isbf);
        #pragma unroll
        for (int reg = 0; reg < 4; reg++){
            int node = n0 + wv * 16 + quad * 4 + reg;
            float v = acc[reg];
            if (node < NN) ft[node * FF + col] = __float2bfloat16(v);
            elp[reg] += v * alv;
            erp[reg] += v * arv;
        }
    }

    #pragma unroll
    for (int reg = 0; reg < 4; reg++){
        float pl = elp[reg], pr = erp[reg];
        #pragma unroll
        for (int off = 1; off < 16; off <<= 1){
            pl += __shfl_xor(pl, off);
            pr += __shfl_xor(pr, off);
        }
        int node = n0 + wv * 16 + quad * 4 + reg;
        if (mcol == 0 && node < NN){ el[node] = pl; er[node] = pr; }
    }
}

// ---------------- MFMA GEMM (layer 3), LDS-FREE: ft3 = X(bf16) @ W3, f32 out ----------------

__global__ __launch_bounds__(256) void k_mgemm3(const void* __restrict__ X, const unsigned short* __restrict__ wt3g,
                                                const void* __restrict__ al, const void* __restrict__ ar,
                                                const int* __restrict__ dflag, float* __restrict__ ft,
                                                float* __restrict__ el, float* __restrict__ er){
    const int isbf = *dflag;
    const int t  = threadIdx.x;
    const int n0 = blockIdx.x * 64;
    const int wv = t >> 6;
    const int lane = t & 63;
    const int quad = lane >> 4;
    const int mcol = lane & 15;
    const int row = n0 + wv * 16 + mcol;
    const int rc  = (row < NN) ? row : 0;

    const unsigned short* xr = (const unsigned short*)X + rc * FF + quad * 8;
    const unsigned short* wr = wt3g + mcol * FF + quad * 8;

    f32x4 acc = {0.f, 0.f, 0.f, 0.f};
    #pragma unroll
    for (int kt = 0; kt < 4; kt++){
        bf16x8 afr = *(const bf16x8*)(xr + kt * 32);
        bf16x8 bfr = *(const bf16x8*)(wr + kt * 32);
        acc = __builtin_amdgcn_mfma_f32_16x16x32_bf16(afr, bfr, acc, 0, 0, 0);
    }

    float alv = ldf(al, mcol, isbf);
    float arv = ldf(ar, mcol, isbf);
    #pragma unroll
    for (int reg = 0; reg < 4; reg++){
        int node = n0 + wv * 16 + quad * 4 + reg;
        float v = acc[reg];
        if (node < NN) ft[node * CC + mcol] = v;
        float pl = v * alv, pr = v * arv;
        #pragma unroll
        for (int off = 1; off < 16; off <<= 1){
            pl += __shfl_xor(pl, off);
            pr += __shfl_xor(pr, off);
        }
        if (mcol == 0 && node < NN){ el[node] = pl; er[node] = pr; }
    }
}

// ---------------- Aggregation (128 feats, bf16 ft): round-0 proven kernel, bf16 output ----------------

__global__ __launch_bounds__(256) void k_agg128(const void* __restrict__ ftv, const float* __restrict__ el,
                                                const float* __restrict__ er, const int* __restrict__ rowptr,
                                                const int* __restrict__ csrsrc, const void* __restrict__ bias,
                                                const int* __restrict__ dflag, unsigned* __restrict__ outp){
    const int isbf = *dflag;
    int lane = threadIdx.x & 63;
    int n = blockIdx.x * 4 + (threadIdx.x >> 6);
    if (n >= NN) return;
    int beg = rowptr[n], end = rowptr[n + 1];
    beg = (beg < 0) ? 0 : (beg > NE ? NE : beg);
    end = (end < beg) ? beg : (end > NE ? NE : end);
    int deg = end - beg;
    float erd = er[n];

    float m = -3.4e38f;
    int   s_c = 0;
    float e_c = 0.f;
    for (int i = beg + lane; i < end; i += 64){
        int s = csrsrc[i];
        if ((unsigned)s >= NN) s = 0;
        float e = el[s] + erd;
        e = (e >= 0.f) ? e : 0.2f * e;
        if (i < beg + 64){ s_c = s; e_c = e; }
        m = fmaxf(m, e);
    }
    #pragma unroll
    for (int off = 32; off; off >>= 1) m = fmaxf(m, __shfl_xor(m, off));

    int jmax = (deg < 64) ? deg : 64;
    float w_c = (lane < jmax) ? __expf(e_c - m) : 0.f;
    float lsum = w_c;
    #pragma unroll
    for (int off = 32; off; off >>= 1) lsum += __shfl_xor(lsum, off);

    const unsigned* ftb = (const unsigned*)ftv;
    float acc0 = 0.f, acc1 = 0.f;
    int j = 0;
    if (jmax >= 8){
        float w[8]; unsigned u[8];
        #pragma unroll
        for (int q = 0; q < 8; q++){
            int s = __builtin_amdgcn_readlane(s_c, q);
            w[q] = rdlanef(w_c, q);
            u[q] = (ftb + s * 64)[lane];
        }
        for (j = 8; j + 8 <= jmax; j += 8){
            float wn[8]; unsigned un[8];
            #pragma unroll
            for (int q = 0; q < 8; q++){
                int s = __builtin_amdgcn_readlane(s_c, j + q);
                wn[q] = rdlanef(w_c, j + q);
                un[q] = (ftb + s * 64)[lane];
            }
            #pragma unroll
            for (int q = 0; q < 8; q++){
                acc0 += w[q] * bflo(u[q]);
                acc1 += w[q] * bfhi(u[q]);
                w[q] = wn[q]; u[q] = un[q];
            }
        }
        #pragma unroll
        for (int q = 0; q < 8; q++){
            acc0 += w[q] * bflo(u[q]);
            acc1 += w[q] * bfhi(u[q]);
        }
    }
    for (; j < jmax; ++j){
        int s = __builtin_amdgcn_readlane(s_c, j);
        float w = rdlanef(w_c, j);
        unsigned u = (ftb + s * 64)[lane];
        acc0 += w * bflo(u); acc1 += w * bfhi(u);
    }
    for (int i = beg + 64; i < end; ++i){
        int s = csrsrc[i];
        if ((unsigned)s >= NN) s = 0;
        float e = el[s] + erd;
        e = (e >= 0.f) ? e : 0.2f * e;
        float w = __expf(e - m);
        unsigned u = (ftb + s * 64)[lane];
        lsum += w;
        acc0 += w * bflo(u); acc1 += w * bfhi(u);
    }
    float inv = 1.f / ((lsum > 0.f) ? lsum : 1.f);
    float o0 = fmaxf(acc0 * inv + ldf(bias, 2 * lane,     isbf), 0.f);
    float o1 = fmaxf(acc1 * inv + ldf(bias, 2 * lane + 1, isbf), 0.f);
    unsigned pk = (unsigned)f2bfu(o0) | ((unsigned)f2bfu(o1) << 16);
    outp[n * 64 + lane] = pk;
}

// ---------------- Aggregation (16 feats, f32 ft): single-pass gather with inline softmax ----------------

__global__ __launch_bounds__(256) void k_agg16(const float* __restrict__ ftv, const float* __restrict__ el,
                                               const float* __restrict__ er, const int* __restrict__ rowptr,
                                               const int* __restrict__ csrsrc, const void* __restrict__ bias,
                                               const int* __restrict__ dflag, void* __restrict__ outp){
    const int isbf = *dflag;
    const int lane = threadIdx.x & 63;
    const int n = blockIdx.x * 4 + (threadIdx.x >> 6);
    if (n >= NN) return;
    int beg = rowptr[n], end = rowptr[n + 1];
    beg = (beg < 0) ? 0 : (beg > NE ? NE : beg);
    end = (end < beg) ? beg : (end > NE ? NE : end);
    const float erd = er[n];

    const int g = lane >> 2;     // edge slot 0..15
    const int c = lane & 3;      // float4 index within 64B row
    const float4* ftq = (const float4*)ftv;
    float a0 = 0.f, a1 = 0.f, a2 = 0.f, a3 = 0.f;
    float lsum = 0.f;

    for (int j = beg; j < end; j += 32){
        #pragma unroll
        for (int q = 0; q < 2; q++){
            int iq = j + q * 16 + g;
            int cq = (iq < end) ? iq : beg;
            int s  = csrsrc[cq];
            if ((unsigned)s >= NN) s = 0;
            float e = el[s] + erd;
            e = (e >= 0.f) ? e : 0.2f * e;
            float w = (iq < end) ? __expf(e) : 0.f;
            float4 u = ftq[(unsigned)s * 4u + c];
            lsum += w;
            a0 += w * u.x; a1 += w * u.y; a2 += w * u.z; a3 += w * u.w;
        }
    }

    // Sum across the 16 groups (lane bits 2-5).
    #pragma unroll
    for (int off = 4; off < 64; off <<= 1){
        a0 += __shfl_xor(a0, off);
        a1 += __shfl_xor(a1, off);
        a2 += __shfl_xor(a2, off);
        a3 += __shfl_xor(a3, off);
        lsum += __shfl_xor(lsum, off);
    }

    if (lane < 4){
        float inv = (lsum > 0.f) ? 1.f / lsum : 0.f;
        float o0 = fmaxf(a0 * inv + ldf(bias, c * 4 + 0, isbf), 0.f);
        float o1 = fmaxf(a1 * inv + ldf(bias, c * 4 + 1, isbf), 0.f);
        float o2 = fmaxf(a2 * inv + ldf(bias, c * 4 + 2, isbf), 0.f);
        float o3 = fmaxf(a3 * inv + ldf(bias, c * 4 + 3, isbf), 0.f);
        if (isbf){
            uint2 pk;
            pk.x = (unsigned)f2bfu(o0) | ((unsigned)f2bfu(o1) << 16);
            pk.y = (unsigned)f2bfu(o2) | ((unsigned)f2bfu(o3) << 16);
            ((uint2*)outp)[n * 4 + c] = pk;
        } else {
            float4 o; o.x = o0; o.y = o1; o.z = o2; o.w = o3;
            ((float4*)outp)[n * 4 + c] = o;
        }
    }
}

// ---------------- host launch ----------------

static size_t align256(size_t x){ return (x + 255) & ~(size_t)255; }

extern "C" void kernel_launch(void* const* d_in, const int* in_sizes, int n_in,
                              void* d_out, int out_size, void* d_ws, size_t ws_size,
                              hipStream_t stream) {
    const void* feat = d_in[0];
    const int*  src  = (const int*)d_in[1];
    const int*  dst  = (const int*)d_in[2];
    const void* W1 = d_in[3];
    const void* al1= d_in[4];
    const void* ar1= d_in[5];
    const void* b1 = d_in[6];
    const void* W2 = d_in[7];
    const void* al2= d_in[8];
    const void* ar2= d_in[9];
    const void* b2 = d_in[10];
    const void* W3 = d_in[11];
    const void* al3= d_in[12];
    const void* ar3= d_in[13];
    const void* b3 = d_in[14];

    // workspace carve
    char* p = (char*)d_ws;
    size_t off = 0;
    auto carve = [&](size_t bytes)->void*{
        void* r = p + off;
        off += align256(bytes);
        return r;
    };
    float* ftA   = (float*)carve((size_t)NN * FF * 4);   // ft buffer: bf16 view (layers 1/2), f32 view (layer 3)
    unsigned* hB = (unsigned*)carve((size_t)NN * FF * 4); // hidden state bf16-packed; bpairs overlays pre-layer-1
    float* el    = (float*)carve((size_t)NN * 4);
    float* er    = (float*)carve((size_t)NN * 4);
    int*   rowptr= (int*)  carve((size_t)(NN + 1) * 4);
    int*   csrsrc= (int*)  carve((size_t)NE * 4);
    int*   bcounts=(int*)  carve((size_t)NB * 4);
    int*   bbase  =(int*)  carve((size_t)(NB + 1) * 4);
    int*   bh     =(int*)  carve((size_t)NB * NBLK * 4);  // per-(bucket,block) hist/offsets, 800KB
    unsigned short* wtg = (unsigned short*)carve((size_t)34816 * 2);  // W1t,W2t,W3t bf16
    int*   dflag  =(int*)  carve(256);
    unsigned* bpairs = (unsigned*)hB;   // overlay: consumed (k_bsort) before hB is first written (agg128-1)
    void*  ftb   = ftA;                 // bf16 ft view (layers 1-2); f32 ft3 view (layer 3)
    (void)ws_size; (void)n_in; (void)in_sizes; (void)out_size;

    dim3 b256(256);
    const int mg_grid   = (NN + 63) / 64;     // 782
    const int node_grid = (NN + 3) / 4;       // 12500

    // 0: zero bucket totals (stream-capturable)
    hipMemsetAsync(bcounts, 0, (size_t)NB * 4, stream);
    // 1: fused prep+bcount (dtype detect, weight transpose, per-block hist + totals; int4 edge loads)
    k_prepcount<<<dim3(NBLK), b256, 0, stream>>>((const unsigned short*)feat, W1, W2, W3, dst,
                                                 dflag, bh, bcounts, wtg);
    // 2: exclusive scan of bucket totals
    k_bscan<<<dim3(1), b256, 0, stream>>>(bcounts, bbase, rowptr);
    // 3: per-(bucket,block) offsets
    k_boffset<<<dim3((NB + 3) / 4), b256, 0, stream>>>(bbase, bh);
    // 4: FAT — bucket scatter (int4 loads, 256 blocks) || layer-1 GEMM (782 blocks)
    k_fat<<<dim3(NBLK + mg_grid), b256, 0, stream>>>(src, dst, bh, bpairs, feat, wtg, al1, ar1,
                                                     dflag, (bf16*)ftb, el, er);
    // 5: in-bucket counting sort with LDS permute -> coalesced csrsrc writes
    k_bsort<<<dim3(NB), b256, 0, stream>>>(bpairs, bbase, rowptr, csrsrc);

    // 6: layer-1 aggregation -> hB (bf16-packed)
    k_agg128<<<dim3(node_grid), b256, 0, stream>>>(ftb, el, er, rowptr, csrsrc, b1, dflag, hB);
    // 7-8: layer 2
    k_mgemm2<<<dim3(mg_grid), b256, 0, stream>>>(hB, wtg + 16384, al2, ar2, dflag, (bf16*)ftb, el, er);
    k_agg128<<<dim3(node_grid), b256, 0, stream>>>(ftb, el, er, rowptr, csrsrc, b2, dflag, hB);
    // 9-10: layer 3
    k_mgemm3<<<dim3(mg_grid), b256, 0, stream>>>(hB, wtg + 32768, al3, ar3, dflag, (float*)ftb, el, er);
    k_agg16<<<dim3(node_grid), b256, 0, stream>>>((const float*)ftb, el, er, rowptr, csrsrc, b3, dflag, d_out);
}